// Round 1
// baseline (376.834 us; speedup 1.0000x reference)
//
#include <hip/hip_runtime.h>

namespace {

constexpr int NS     = 51;
constexpr int NSP    = 52;   // padded row stride (col 51 is zero padding)
constexpr int NITERS = 50;

// constexpr double-precision exp (range-reduce + Taylor), accurate far beyond f32
constexpr double cexp_d(double x) {
  const double LN2 = 0.6931471805599453094172321214582;
  const double t = x / LN2;
  const int k = (int)(t >= 0.0 ? t + 0.5 : t - 0.5);
  const double r = x - (double)k * LN2;
  double term = 1.0, sum = 1.0;
  for (int i = 1; i <= 30; ++i) { term *= r / (double)i; sum += term; }
  double p = 1.0;
  if (k >= 0) { for (int i = 0; i < k;  ++i) p *= 2.0; }
  else        { for (int i = 0; i < -k; ++i) p *= 0.5; }
  return sum * p;
}

struct Tbl { float v[NS * NSP]; };

// SSS[i][j] = exp(-f32(DELTAW[i][j]) / f32(RGAS*T)); DELTAW computed in double
// like the numpy reference. SSS is symmetric (sigma_acc[i,j]=s[max], sigma_don=s[min]).
constexpr Tbl make_tbl() {
  Tbl T{};
  double sq = 2.7;                       // sqrt(7.5) by Newton
  for (int i = 0; i < 50; ++i) sq = 0.5 * (sq + 7.5 / sq);
  const double alpha = 0.3 * (7.5 * sq) / 0.0002395;   // 0.3*AEFF^1.5/EO
  const double fpol  = (3.667 - 1.0) / (3.667 + 0.5);
  const double ap    = fpol * alpha;                   // alpha_prime
  const double RGAST = (8.3144598 / 4184.0) * 623.15;
  const float  rgast_f = (float)RGAST;
  for (int i = 0; i < NS; ++i) {
    for (int j = 0; j < NS; ++j) {
      const double si = -0.025 + 0.001 * (double)i;
      const double sj = -0.025 + 0.001 * (double)j;
      const double smax = si > sj ? si : sj;
      const double smin = si < sj ? si : sj;
      double acc = smax - 0.0084; if (acc < 0.0) acc = 0.0;   // max(0, sigma_acc - SIG_HB)
      double don = smin + 0.0084; if (don > 0.0) don = 0.0;   // min(0, sigma_don + SIG_HB)
      const double dw = ap * 0.5 * (si + sj) * (si + sj) + 85580.0 * acc * don;
      const float dwf = (float)dw;
      const float arg = -(dwf / rgast_f);
      T.v[i * NSP + j] = (float)cexp_d((double)arg);
    }
    T.v[i * NSP + NS] = 0.0f;            // padding column -> harmless garbage lane m=51
  }
  return T;
}

constexpr Tbl TBL = make_tbl();

} // namespace

// One lane per (element, task): even lane = pure solve, odd lane = mix solve.
// Hot loop is lane-uniform (same SSS literals for all lanes) -> no divergence.
__global__ __launch_bounds__(256) void cosmo_kernel(
    const float* __restrict__ my_sigma,   // [B,51]
    const float* __restrict__ v_comp,     // [B]
    const float* __restrict__ vt_sigma,   // [B,51,2]
    const float* __restrict__ v_vt,       // [B]
    float* __restrict__ out,              // [B]
    int B)
{
  const int t = blockIdx.x * 256 + threadIdx.x;
  const int e = t >> 1;
  if (e >= B) return;
  const int task = t & 1;

  const float* __restrict__ myp = my_sigma + (size_t)e * NS;
  const float* __restrict__ vtp = vt_sigma + (size_t)e * NS * 2;

  float w[NS];
  float A0 = 0.f, A1 = 0.f;
#pragma unroll
  for (int n = 0; n < NS; ++n) {
    const float a = myp[n];
    const float b = vtp[2 * n + 1];
    A0 += a;
    A1 += b;
    w[n] = task ? (0.235f * a + 0.765f * b) : a;
  }
  const float den = task ? (0.235f * A0 + 0.765f * A1) : A0;
#pragma unroll
  for (int n = 0; n < NS; ++n) w[n] = w[n] / den;

  float G[NS];
#pragma unroll
  for (int n = 0; n < NS; ++n) G[n] = 1.0f;

  // 50-step damped fixed point: G <- 0.5*(G + 1/(SSS @ (w*G)))
#pragma unroll 1
  for (int it = 0; it < NITERS; ++it) {
    float H[NS];
#pragma unroll
    for (int n = 0; n < NS; ++n) H[n] = w[n] * G[n];
    // m unrolled x4: 4 independent FMA chains hide the 4-cyc dep latency.
    // Table reads constant-fold to FMA literals (TBL is constexpr).
#pragma unroll
    for (int m0 = 0; m0 < NS; m0 += 4) {
      float d0 = 0.f, d1 = 0.f, d2 = 0.f, d3 = 0.f;
#pragma unroll
      for (int n = 0; n < NS; ++n) {
        const float h = H[n];
        d0 += TBL.v[n * NSP + m0 + 0] * h;   // SSS[m0+k][n] via symmetry
        d1 += TBL.v[n * NSP + m0 + 1] * h;
        d2 += TBL.v[n * NSP + m0 + 2] * h;
        d3 += TBL.v[n * NSP + m0 + 3] * h;
      }
      G[m0] = 0.5f * (G[m0] + __builtin_amdgcn_rcpf(d0));
      if (m0 + 1 < NS) G[m0 + 1] = 0.5f * (G[m0 + 1] + __builtin_amdgcn_rcpf(d1));
      if (m0 + 2 < NS) G[m0 + 2] = 0.5f * (G[m0 + 2] + __builtin_amdgcn_rcpf(d2));
      if (m0 + 3 < NS) G[m0 + 3] = 0.5f * (G[m0 + 3] + __builtin_amdgcn_rcpf(d3));
    }
  }

  // S = sum_n psigma_pure[n] * ln(Gamma[n])  (weights are ALWAYS the pure psigma)
  float S = 0.f;
#pragma unroll
  for (int n = 0; n < NS; ++n) {
    const float p = myp[n] / A0;
    S += p * logf(G[n]);
  }

  // lane pair (2e, 2e+1) exchange: even lane holds S_pure, gets S_mix
  const float So = __shfl_xor(S, 1, 64);

  if (task == 0) {
    const float lng_resid = A0 / 7.5f * (So - S);
    const float v0  = v_comp[e];
    const float v1v = v_vt[e];
    const float q0 = A0 / 79.53f, q1 = A1 / 79.53f;
    const float r0 = v0 / 66.69f, r1 = v1v / 66.69f;
    const float xq = 0.235f * q0 + 0.765f * q1;
    const float xr = 0.235f * r0 + 0.765f * r1;
    const float theta = 0.235f * q0 / xq;
    const float phi   = 0.235f * r0 / xr;
    const float l0 = 5.0f * (r0 - q0) - (r0 - 1.0f);
    const float l1 = 5.0f * (r1 - q1) - (r1 - 1.0f);
    const float xl = 0.235f * l0 + 0.765f * l1;
    const float lng_comb = logf(phi / 0.235f) + 5.0f * q0 * logf(theta / phi)
                         + l0 - (phi / 0.235f) * xl;
    out[e] = lng_resid + lng_comb;
  }
}

extern "C" void kernel_launch(void* const* d_in, const int* in_sizes, int n_in,
                              void* d_out, int out_size, void* d_ws, size_t ws_size,
                              hipStream_t stream) {
  const float* my  = (const float*)d_in[0];
  const float* vc  = (const float*)d_in[1];
  const float* vts = (const float*)d_in[2];
  const float* vvt = (const float*)d_in[3];
  float* out = (float*)d_out;
  const int B = in_sizes[1];          // v_compound is [B]
  const int threads = 2 * B;
  const int block = 256;
  const int grid = (threads + block - 1) / block;
  cosmo_kernel<<<grid, block, 0, stream>>>(my, vc, vts, vvt, out, B);
}